// Round 13
// baseline (90.713 us; speedup 1.0000x reference)
//
#include <hip/hip_runtime.h>
#include <math.h>
#include <stdint.h>

// ---------------------------------------------------------------------------
// TemporalRelationGraph forward, MI355X — bf16 MFMA pipeline, round 13
// r12 frontier + TAIL SHORTENING: out_reduce deleted. head_fused pre-writes
// counted biases into out (independent blocks, run in head's shadow);
// out_atomic accumulates split-K partials straight into out via
// global_atomic_add_f32. Critical chain: head -> p_mfma -> hsum -> out_atomic.
//   head_fused : blk<256 gram | <1536 W1T | <1728 W2T | <1984 out=bias
//   p_mfma     : P(2048x5120 bf16) = Rbf @ W1T^T (dense, XCD-swizzled)
//   hsum_all   : Hsum(2048x2048 bf16) windowed relu-sums (short2)
//   out_atomic : split-K=4, atomicAdd into out (bias-preloaded)
// Train/test plans identical for SEQ=8,NF=4,SUB=10 -> is_test ignored.
// ---------------------------------------------------------------------------

typedef __attribute__((ext_vector_type(8))) short short8v;
typedef __attribute__((ext_vector_type(4))) short short4v;
typedef __attribute__((ext_vector_type(4))) float f32x4;

__device__ __forceinline__ short f2bf(float f) {
  uint32_t u = __float_as_uint(f);
  u += 0x7fffu + ((u >> 16) & 1u);      // RNE
  return (short)(u >> 16);
}
__device__ __forceinline__ float bf2f(short s) {
  return __uint_as_float(((uint32_t)(uint16_t)s) << 16);
}
__device__ __forceinline__ void gload16(const void* g, void* l) {
  __builtin_amdgcn_global_load_lds(
      (const __attribute__((address_space(1))) void*)g,
      (__attribute__((address_space(3))) void*)l, 16, 0, 0);
}

__device__ const int8_t ROWS4[12][5] = {
  {3, 0,1,2,3},
  {4, 0,1,2,3},{4, 1,2,3,4},
  {5, 0,1,2,3},{5, 1,2,3,4},{5, 2,3,4,5},
  {6, 0,1,2,3},{6, 1,2,3,4},{6, 2,3,4,5},{6, 3,4,5,6},
  {7, 0,2,4,6},{7, 1,3,5,7},
};
__device__ const int8_t ROWS3[15][4] = {
  {2, 0,1,2},
  {3, 0,1,2},{3, 1,2,3},
  {4, 0,1,2},{4, 1,2,3},{4, 2,3,4},
  {5, 0,2,4},{5, 1,3,5},
  {6, 0,2,4},{6, 1,3,5},{6, 2,4,6},
  {7, 0,2,4},{7, 1,3,5},{7, 2,4,6},{7, 3,5,7},
};
__device__ const int8_t ROWS2[19][3] = {
  {1, 0,1},
  {2, 0,1},{2, 1,2},
  {3, 0,2},{3, 1,3},
  {4, 0,2},{4, 1,3},{4, 2,4},
  {5, 0,3},{5, 1,4},{5, 2,5},
  {6, 0,3},{6, 1,4},{6, 2,5},{6, 3,6},
  {7, 0,4},{7, 1,5},{7, 2,6},{7, 3,7},
};
__device__ const int8_t ROWS1[36][2] = {
  {0,0},
  {1,0},{1,1},
  {2,0},{2,1},{2,2},
  {3,0},{3,1},{3,2},{3,3},
  {4,0},{4,1},{4,2},{4,3},{4,4},
  {5,0},{5,1},{5,2},{5,3},{5,4},{5,5},
  {6,0},{6,1},{6,2},{6,3},{6,4},{6,5},{6,6},
  {7,0},{7,1},{7,2},{7,3},{7,4},{7,5},{7,6},{7,7},
};
// window counts per (t, scale-index): si 0->s4, 1->s3, 2->s2, 3->s1
__device__ const float CNT[8][4] = {
  {0,0,0,1},{0,0,1,2},{0,1,2,3},{1,2,2,4},
  {2,3,3,5},{3,2,3,6},{4,3,4,7},{2,4,4,8},
};

// LDS offsets (bytes) for the gram path (79 KB); prep overlays the head.
#define GV_FH    0            // Fh [80 rows][128 bf16], swizzled, 20480 B
#define GV_FL    20480        // Fl, 20480 B
#define GV_S     40960        // S [80][84] f32, 26880 B
#define GV_XSUM  67840        // xsum [8][256] f32, 8192 B
#define GV_VB    76032        // vbuf [2][3][84] f32, 2016 B
#define GV_UU    78048        // uu [3][80] f32, 960 B
#define GV_SCAL  79008        // 12 f32
#define GV_SZ    79056

// ---------------------------------------------------------------------------
// Fat head kernel, 256 threads.
//   blk <  256   : gram_var (one block per batch)
//   blk < 1536   : W1T 64x64 transpose tile (LDS stride 65, conflict-free)
//   blk < 1728   : W2T build
//   blk < 1984   : out = counted bias (8 rows/block)
__global__ __launch_bounds__(256) void head_fused(
    const float* __restrict__ init, const float* __restrict__ graph,
    const float* __restrict__ w1_4, const float* __restrict__ w1_3,
    const float* __restrict__ w1_2, const float* __restrict__ w1_1,
    const float* __restrict__ w2a, const float* __restrict__ w2b,
    const float* __restrict__ w2c, const float* __restrict__ w2d,
    const float* __restrict__ b2a, const float* __restrict__ b2b,
    const float* __restrict__ b2c, const float* __restrict__ b2d,
    short* __restrict__ Rbuf, short* __restrict__ W1T, short* __restrict__ W2T,
    float* __restrict__ out)
{
  __shared__ __align__(16) char smem[GV_SZ];
  const int tid = threadIdx.x;
  const int blk = blockIdx.x;

  if (blk >= 256) {
    if (blk < 1536) {
      // ---- W1T transpose: LDS stride 65 floats (2-way bank alias = free) ----
      float* sh = (float*)smem;                 // [64][65] = 16.6 KB
      const int pb = blk - 256;                 // 0..1279
      const int slice = pb >> 7, rem = pb & 127;
      const int k0 = (rem & 15) * 64, c0 = (rem >> 4) * 64;
      const float* W1; int j;
      if (slice < 4)      { W1 = w1_4; j = slice; }
      else if (slice < 7) { W1 = w1_3; j = slice - 4; }
      else if (slice < 9) { W1 = w1_2; j = slice - 7; }
      else                { W1 = w1_1; j = 0; }
#pragma unroll
      for (int q = tid; q < 1024; q += 256) {
        int r = q >> 4, cq = (q & 15) * 4;
        f32x4 v = *(const f32x4*)(W1 + (size_t)(j * 1024 + k0 + r) * 512 + c0 + cq);
        sh[r * 65 + cq + 0] = v.x; sh[r * 65 + cq + 1] = v.y;
        sh[r * 65 + cq + 2] = v.z; sh[r * 65 + cq + 3] = v.w;
      }
      __syncthreads();
#pragma unroll
      for (int q = tid; q < 1024; q += 256) {
        int cc = q >> 4, kq = (q & 15) * 4;
        short4v sv;
#pragma unroll
        for (int m = 0; m < 4; ++m) sv[m] = f2bf(sh[(kq + m) * 65 + cc]);
        *(short4v*)&W1T[(size_t)(slice * 512 + c0 + cc) * 1024 + k0 + kq] = sv;
      }
    } else if (blk < 1728) {
      // ---- W2T build: col-padded [192][2048] ----
#pragma unroll
      for (int h = 0; h < 2; ++h) {
        int idx = (blk - 1536) * 2048 + tid * 8 + h * 4;
        int col = idx >> 11, kg = idx & 2047;
        int si = kg >> 9, kr = kg & 511;
        const float* w = (si == 0) ? w2a : (si == 1) ? w2b : (si == 2) ? w2c : w2d;
        short4v sv;
#pragma unroll
        for (int q = 0; q < 4; ++q)
          sv[q] = (col < 174) ? f2bf(w[(size_t)(kr + q) * 174 + col]) : (short)0;
        *(short4v*)&W2T[idx] = sv;
      }
    } else {
      // ---- out = counted bias (8 rows per block; out_atomic adds onto it) ----
      const int row0 = (blk - 1728) * 8;
      const int col = tid;
      if (col < 174) {
        float ba = b2a[col], bb = b2b[col], bc = b2c[col], bd = b2d[col];
#pragma unroll
        for (int r = 0; r < 8; ++r) {
          // row0 is 8-aligned so t == r
          out[(size_t)(row0 + r) * 174 + col] =
              CNT[r][0] * ba + CNT[r][1] * bb + CNT[r][2] * bc + CNT[r][3] * bd;
        }
      }
    }
    return;
  }

  // ================= gram_var path (r7 verified) =================
  short* Fh  = (short*)(smem + GV_FH);
  short* Fl  = (short*)(smem + GV_FL);
  float* Sm  = (float*)(smem + GV_S);
  float* xsm = (float*)(smem + GV_XSUM);
  float* vb  = (float*)(smem + GV_VB);
  float* uum = (float*)(smem + GV_UU);
  float* scal= (float*)(smem + GV_SCAL);

  const int lane = tid & 63, w = tid >> 6;
  const int b = blk;
  const float* fb = init + (size_t)b * 80 * 256;

  int ti_[7], tj_[7];
#pragma unroll
  for (int q = 0; q < 7; ++q) {
    int tt = w + q * 4;
    int t5 = (tt < 25) ? tt : 0;
    ti_[q] = t5 / 5; tj_[q] = t5 % 5;
  }

  f32x4 acc[7];
#pragma unroll
  for (int q = 0; q < 7; ++q) acc[q] = (f32x4){0.f, 0.f, 0.f, 0.f};

  for (int ch = 0; ch < 2; ++ch) {
    __syncthreads();
    {
      const int t = tid >> 5, kq = tid & 31;
      const float* src = fb + (size_t)(t * 10) * 256 + ch * 128 + kq * 4;
      f32x4 sum = (f32x4){0.f, 0.f, 0.f, 0.f};
#pragma unroll
      for (int o = 0; o < 10; ++o) {
        f32x4 v = *(const f32x4*)(src + (size_t)o * 256);
        int r = t * 10 + o;
        int byte8 = r * 256 + ((kq * 8) ^ ((r & 7) << 4));
        short4v hv, lv;
#pragma unroll
        for (int e = 0; e < 4; ++e) {
          short h = f2bf(v[e]);
          hv[e] = h;
          lv[e] = f2bf(v[e] - bf2f(h));
        }
        *(short4v*)((char*)Fh + byte8) = hv;
        *(short4v*)((char*)Fl + byte8) = lv;
        sum += v;
      }
      *(f32x4*)(xsm + t * 256 + ch * 128 + kq * 4) = sum;
    }
    __syncthreads();

#pragma unroll
    for (int ks = 0; ks < 4; ++ks) {
      const int koff2 = (ks * 32 + (lane >> 4) * 8) * 2;
#pragma unroll
      for (int q = 0; q < 7; ++q) {
        const int tt = w + q * 4;
        if (tt < 25) {
          int ra = ti_[q] * 16 + (lane & 15);
          int rb = tj_[q] * 16 + (lane & 15);
          int ba = ra * 256 + (koff2 ^ ((ra & 7) << 4));
          int bb = rb * 256 + (koff2 ^ ((rb & 7) << 4));
          short8v ah = *(const short8v*)((char*)Fh + ba);
          short8v al = *(const short8v*)((char*)Fl + ba);
          short8v bh = *(const short8v*)((char*)Fh + bb);
          short8v bl = *(const short8v*)((char*)Fl + bb);
          acc[q] = __builtin_amdgcn_mfma_f32_16x16x32_bf16(ah, bh, acc[q], 0, 0, 0);
          acc[q] = __builtin_amdgcn_mfma_f32_16x16x32_bf16(ah, bl, acc[q], 0, 0, 0);
          acc[q] = __builtin_amdgcn_mfma_f32_16x16x32_bf16(al, bh, acc[q], 0, 0, 0);
        }
      }
    }
  }

#pragma unroll
  for (int q = 0; q < 7; ++q) {
    const int tt = w + q * 4;
    if (tt < 25) {
      int row0 = ti_[q] * 16 + (lane >> 4) * 4;
      int col = tj_[q] * 16 + (lane & 15);
#pragma unroll
      for (int r = 0; r < 4; ++r) Sm[(row0 + r) * 84 + col] = acc[q][r];
    }
  }
  if (tid < 240) vb[(0 * 3 + tid / 80) * 84 + (tid % 80)] = 1.0f;
  __syncthreads();

  const int pk = (tid < 240) ? tid / 80 : 0;
  const int pi = (tid < 240) ? tid % 80 : 0;
  int cur = 0;
  for (int it = 0; it < 5; ++it) {
    const bool last = (it == 4);
    float u = 0.f;
    if (tid < 240) {
      const float* Si = Sm + pi * 84;
      const float* vk = vb + (cur * 3 + pk) * 84;
#pragma unroll
      for (int q2 = 0; q2 < 20; ++q2) {
        f32x4 aa = *(const f32x4*)(Si + q2 * 4);
        f32x4 vv = *(const f32x4*)(vk + q2 * 4);
        u += aa.x * vv.x + aa.y * vv.y + aa.z * vv.z + aa.w * vv.w;
      }
    } else if (tid < 246) {
      int w2 = tid - 240;
      int k = (w2 < 3) ? w2 : w2 - 3;
      const float* vk = vb + (cur * 3 + k) * 84;
      float s = 0.f;
      if (w2 < 3) {
        for (int j2 = 0; j2 < 80; ++j2) s += vk[j2];
        scal[k] = s;                      // sigma
      } else {
        const float* Sk = Sm + k * 84;
        for (int j2 = 0; j2 < 80; ++j2) s += Sk[j2] * vk[j2];
        scal[3 + k] = s;                  // tau
      }
    }
    __syncthreads();
    if (tid < 240) {
      float sg = scal[pk], tu = scal[3 + pk];
      float un = u - Sm[pi * 84 + pk] * sg - tu + Sm[pk * 84 + pk] * sg;
      if (!last) vb[((cur ^ 1) * 3 + pk) * 84 + pi] = un * 6.103515625e-05f;  // 2^-14
      else       uum[pk * 80 + pi] = un;
    }
    __syncthreads();
    if (!last) cur ^= 1;
  }

  if (tid < 192) {
    const int k = tid >> 6, ln = tid & 63;
    float v1 = vb[(cur * 3 + k) * 84 + ln];
    float u1 = uum[k * 80 + ln];
    float a = u1 * v1, b2 = v1 * v1;
    if (ln < 16) {
      float v2 = vb[(cur * 3 + k) * 84 + 64 + ln];
      float u2 = uum[k * 80 + 64 + ln];
      a += u2 * v2; b2 += v2 * v2;
    }
#pragma unroll
    for (int m = 32; m >= 1; m >>= 1) {
      a += __shfl_xor(a, m);
      b2 += __shfl_xor(b2, m);
    }
    if (ln == 0) scal[9 + k] = a / b2;    // lambda
  }
  __syncthreads();
  if (tid == 0) {
    float L0 = -0.1f * scal[9], L1 = -0.1f * scal[10], L2 = -0.1f * scal[11];
    float m = fmaxf(L0, fmaxf(L1, L2));
    float e0 = expf(L0 - m), e1 = expf(L1 - m), e2 = expf(L2 - m);
    float inv = 1.0f / (e0 + e1 + e2);
    scal[6] = e0 * inv; scal[7] = e1 * inv; scal[8] = e2 * inv;
  }
  __syncthreads();

  {
    const float w0 = scal[6], w1 = scal[7], w2 = scal[8];
    const int d0 = (tid & 63) * 4;
#pragma unroll
    for (int p = 0; p < 2; ++p) {
      const int t = p * 4 + (tid >> 6);
      f32x4 xs = *(const f32x4*)(xsm + t * 256 + d0);
      f32x4 c0 = *(const f32x4*)(fb + 0 * 256 + d0);
      f32x4 c1 = *(const f32x4*)(fb + 1 * 256 + d0);
      f32x4 c2 = *(const f32x4*)(fb + 2 * 256 + d0);
      f32x4 go = *(const f32x4*)(graph + (size_t)(b * 8 + t) * 256 + d0);
      size_t rb = ((size_t)(b * 8 + t)) * 1024;
      short4v s0, s1, s2, s3;
#pragma unroll
      for (int q = 0; q < 4; ++q) {
        float xq = xs[q];
        s0[q] = f2bf(fmaxf(w0 * (xq - 10.f * c0[q]), 0.f));
        s1[q] = f2bf(fmaxf(w1 * (xq - 10.f * c1[q]), 0.f));
        s2[q] = f2bf(fmaxf(w2 * (xq - 10.f * c2[q]), 0.f));
        s3[q] = f2bf(fmaxf(go[q], 0.f));
      }
      *(short4v*)&Rbuf[rb + 0 + d0]   = s0;
      *(short4v*)&Rbuf[rb + 256 + d0] = s1;
      *(short4v*)&Rbuf[rb + 512 + d0] = s2;
      *(short4v*)&Rbuf[rb + 768 + d0] = s3;
    }
  }
}

// ---------------------------------------------------------------------------
// P(2048 x 5120) bf16 = Rbf(2048x1024) @ W1T^T; 128x128 tile, BK=32, 4 waves.
__global__ __launch_bounds__(256) void p_mfma(
    const short* __restrict__ A, const short* __restrict__ W1T,
    short* __restrict__ P)
{
  __shared__ short As[128 * 32];
  __shared__ short Bs[128 * 32];
  const int id = blockIdx.x + blockIdx.y * 40;     // 640 = 8 XCD * 80
  const int nid = (id & 7) * 80 + (id >> 3);
  const int bx = nid >> 4, by = nid & 15;
  const int tid = threadIdx.x, lane = tid & 63, w = tid >> 6;
  const int wr = w >> 1, wc = w & 1;
  const int rowBase = by * 128;
  const short* Bp = W1T + (size_t)bx * 128 * 1024;
  const int rA = w * 16 + (lane >> 2);
  const int kkA = (lane & 3) * 8;

  f32x4 acc[4][4];
#pragma unroll
  for (int m = 0; m < 4; ++m)
#pragma unroll
    for (int n = 0; n < 4; ++n) acc[m][n] = (f32x4){0.f, 0.f, 0.f, 0.f};

  for (int k0 = 0; k0 < 1024; k0 += 32) {
    __syncthreads();
    gload16(A + (size_t)(rowBase + rA) * 1024 + k0 + kkA, As + w * 512);
    gload16(A + (size_t)(rowBase + 64 + rA) * 1024 + k0 + kkA, As + 2048 + w * 512);
    gload16(Bp + (size_t)rA * 1024 + k0 + kkA, Bs + w * 512);
    gload16(Bp + (size_t)(64 + rA) * 1024 + k0 + kkA, Bs + 2048 + w * 512);
    __syncthreads();
    short8v a[4], bv[4];
#pragma unroll
    for (int m = 0; m < 4; ++m)
      a[m] = *(const short8v*)(As + (wr * 64 + m * 16 + (lane & 15)) * 32 + (lane >> 4) * 8);
#pragma unroll
    for (int n = 0; n < 4; ++n)
      bv[n] = *(const short8v*)(Bs + (wc * 64 + n * 16 + (lane & 15)) * 32 + (lane >> 4) * 8);
#pragma unroll
    for (int m = 0; m < 4; ++m)
#pragma unroll
      for (int n = 0; n < 4; ++n)
        acc[m][n] = __builtin_amdgcn_mfma_f32_16x16x32_bf16(a[m], bv[n], acc[m][n], 0, 0, 0);
  }

  const int colG = bx * 128 + wc * 64;
#pragma unroll
  for (int m = 0; m < 4; ++m) {
    int row = rowBase + wr * 64 + m * 16 + (lane >> 4) * 4;
#pragma unroll
    for (int n = 0; n < 4; ++n) {
      int col = colG + n * 16 + (lane & 15);
#pragma unroll
      for (int r = 0; r < 4; ++r)
        P[(size_t)(row + r) * 5120 + col] = f2bf(acc[m][n][r]);
    }
  }
}

// ---------------------------------------------------------------------------
// Hsum[row][si*512+c] bf16; thread owns 2 consecutive cols (short2 loads).
__global__ __launch_bounds__(256) void hsum_all(
    const short* __restrict__ P,
    const float* __restrict__ b1a, const float* __restrict__ b1b,
    const float* __restrict__ b1c, const float* __restrict__ b1d,
    short* __restrict__ Hsum)
{
  const int row = blockIdx.x, t = row & 7, base = row - t;
  const int c0 = threadIdx.x * 2;
  const size_t prow = (size_t)base * 5120;

  {  // si=0, s=4
    float2 bb = *(const float2*)(b1a + c0);
    float a0 = 0.f, a1 = 0.f;
    for (int r = 0; r < 12; ++r) {
      if (ROWS4[r][0] != t) continue;
      float h0 = bb.x, h1 = bb.y;
#pragma unroll
      for (int jj = 0; jj < 4; ++jj) {
        const short2 pv = *(const short2*)(P + prow + (size_t)ROWS4[r][1 + jj] * 5120 + jj * 512 + c0);
        h0 += bf2f(pv.x); h1 += bf2f(pv.y);
      }
      a0 += fmaxf(h0, 0.f); a1 += fmaxf(h1, 0.f);
    }
    uint32_t wv = (uint32_t)(uint16_t)f2bf(a0) | ((uint32_t)(uint16_t)f2bf(a1) << 16);
    *(uint32_t*)&Hsum[(size_t)row * 2048 + c0] = wv;
  }
  {  // si=1, s=3
    float2 bb = *(const float2*)(b1b + c0);
    float a0 = 0.f, a1 = 0.f;
    for (int r = 0; r < 15; ++r) {
      if (ROWS3[r][0] != t) continue;
      float h0 = bb.x, h1 = bb.y;
#pragma unroll
      for (int jj = 0; jj < 3; ++jj) {
        const short2 pv = *(const short2*)(P + prow + (size_t)ROWS3[r][1 + jj] * 5120 + 2048 + jj * 512 + c0);
        h0 += bf2f(pv.x); h1 += bf2f(pv.y);
      }
      a0 += fmaxf(h0, 0.f); a1 += fmaxf(h1, 0.f);
    }
    uint32_t wv = (uint32_t)(uint16_t)f2bf(a0) | ((uint32_t)(uint16_t)f2bf(a1) << 16);
    *(uint32_t*)&Hsum[(size_t)row * 2048 + 512 + c0] = wv;
  }
  {  // si=2, s=2
    float2 bb = *(const float2*)(b1c + c0);
    float a0 = 0.f, a1 = 0.f;
    for (int r = 0; r < 19; ++r) {
      if (ROWS2[r][0] != t) continue;
      float h0 = bb.x, h1 = bb.y;
#pragma unroll
      for (int jj = 0; jj < 2; ++jj) {
        const short2 pv = *(const short2*)(P + prow + (size_t)ROWS2[r][1 + jj] * 5120 + 3584 + jj * 512 + c0);
        h0 += bf2f(pv.x); h1 += bf2f(pv.y);
      }
      a0 += fmaxf(h0, 0.f); a1 += fmaxf(h1, 0.f);
    }
    uint32_t wv = (uint32_t)(uint16_t)f2bf(a0) | ((uint32_t)(uint16_t)f2bf(a1) << 16);
    *(uint32_t*)&Hsum[(size_t)row * 2048 + 1024 + c0] = wv;
  }
  {  // si=3, s=1
    float2 bb = *(const float2*)(b1d + c0);
    float a0 = 0.f, a1 = 0.f;
    for (int r = 0; r < 36; ++r) {
      if (ROWS1[r][0] != t) continue;
      const short2 pv = *(const short2*)(P + prow + (size_t)ROWS1[r][1] * 5120 + 4608 + c0);
      a0 += fmaxf(bb.x + bf2f(pv.x), 0.f);
      a1 += fmaxf(bb.y + bf2f(pv.y), 0.f);
    }
    uint32_t wv = (uint32_t)(uint16_t)f2bf(a0) | ((uint32_t)(uint16_t)f2bf(a1) << 16);
    *(uint32_t*)&Hsum[(size_t)row * 2048 + 1536 + c0] = wv;
  }
}

// ---------------------------------------------------------------------------
// Split-K out GEMM, atomic accumulate into bias-preloaded out.
__global__ __launch_bounds__(256) void out_atomic(
    const short* __restrict__ H, const short* __restrict__ W2T,
    float* __restrict__ out)
{
  __shared__ short As[128 * 32];
  __shared__ short Bs[64 * 32];
  const int tid = threadIdx.x, lane = tid & 63, w = tid >> 6;
  const int wr = w >> 1, wc = w & 1;
  const int rowBase = blockIdx.y * 128, colBase = blockIdx.x * 64;
  const int kBase = blockIdx.z * 512;
  const int rA = w * 16 + (lane >> 2);
  const int kkA = (lane & 3) * 8;

  f32x4 acc[4][2];
#pragma unroll
  for (int m = 0; m < 4; ++m)
#pragma unroll
    for (int n = 0; n < 2; ++n) acc[m][n] = (f32x4){0.f, 0.f, 0.f, 0.f};

  for (int k0 = 0; k0 < 512; k0 += 32) {
    const int kg = kBase + k0;
    __syncthreads();
    gload16(H + (size_t)(rowBase + rA) * 2048 + kg + kkA, As + w * 512);
    gload16(H + (size_t)(rowBase + 64 + rA) * 2048 + kg + kkA, As + 2048 + w * 512);
    gload16(W2T + (size_t)(colBase + rA) * 2048 + kg + kkA, Bs + w * 512);
    __syncthreads();
    short8v a[4], bv[2];
#pragma unroll
    for (int m = 0; m < 4; ++m)
      a[m] = *(const short8v*)(As + (wr * 64 + m * 16 + (lane & 15)) * 32 + (lane >> 4) * 8);
#pragma unroll
    for (int n = 0; n < 2; ++n)
      bv[n] = *(const short8v*)(Bs + (wc * 32 + n * 16 + (lane & 15)) * 32 + (lane >> 4) * 8);
#pragma unroll
    for (int m = 0; m < 4; ++m)
#pragma unroll
      for (int n = 0; n < 2; ++n)
        acc[m][n] = __builtin_amdgcn_mfma_f32_16x16x32_bf16(a[m], bv[n], acc[m][n], 0, 0, 0);
  }

#pragma unroll
  for (int n = 0; n < 2; ++n) {
    int col = colBase + wc * 32 + n * 16 + (lane & 15);
    if (col >= 174) continue;
#pragma unroll
    for (int m = 0; m < 4; ++m) {
      int row0 = rowBase + wr * 64 + m * 16 + (lane >> 4) * 4;
#pragma unroll
      for (int r = 0; r < 4; ++r)
        unsafeAtomicAdd(&out[(size_t)(row0 + r) * 174 + col], acc[m][n][r]);
    }
  }
}

// ---------------------------------------------------------------------------
extern "C" void kernel_launch(void* const* d_in, const int* in_sizes, int n_in,
                              void* d_out, int out_size, void* d_ws, size_t ws_size,
                              hipStream_t stream) {
  const float* graph = (const float*)d_in[0];
  const float* init  = (const float*)d_in[1];
  const float* w1[4] = {(const float*)d_in[3],  (const float*)d_in[7],
                        (const float*)d_in[11], (const float*)d_in[15]};
  const float* b1[4] = {(const float*)d_in[4],  (const float*)d_in[8],
                        (const float*)d_in[12], (const float*)d_in[16]};
  const float* w2[4] = {(const float*)d_in[5],  (const float*)d_in[9],
                        (const float*)d_in[13], (const float*)d_in[17]};
  const float* b2[4] = {(const float*)d_in[6],  (const float*)d_in[10],
                        (const float*)d_in[14], (const float*)d_in[18]};
  float* out = (float*)d_out;

  char* ws = (char*)d_ws;
  short* Rbf  = (short*)(ws + 0);                    // 4 MiB   (dead after p_mfma)
  short* W1T  = (short*)(ws + ((size_t)4  << 20));   // 10 MiB  (dead after p_mfma)
  short* P    = (short*)(ws + ((size_t)14 << 20));   // 20 MiB  (dead after hsum_all)
  short* W2T  = (short*)(ws + ((size_t)34 << 20));   // 0.75 MiB
  short* Hsum = (short*)(ws + 0);                    // 8 MiB   (over Rbf/W1T head)

  head_fused<<<1984, 256, 0, stream>>>(init, graph,
                                       w1[0], w1[1], w1[2], w1[3],
                                       w2[0], w2[1], w2[2], w2[3],
                                       b2[0], b2[1], b2[2], b2[3],
                                       Rbf, W1T, W2T, out);

  p_mfma<<<dim3(40, 16), 256, 0, stream>>>(Rbf, W1T, P);

  hsum_all<<<2048, 256, 0, stream>>>(P, b1[0], b1[1], b1[2], b1[3], Hsum);

  out_atomic<<<dim3(3, 16, 4), 256, 0, stream>>>(Hsum, W2T, out);
}

// Round 14
// 86.980 us; speedup vs baseline: 1.0429x; 1.0429x over previous
//
#include <hip/hip_runtime.h>
#include <math.h>
#include <stdint.h>

// ---------------------------------------------------------------------------
// TemporalRelationGraph forward, MI355X — bf16 MFMA pipeline
// FINAL: round-12 frontier configuration (best measured: 87.3 us).
//   head_fused : blk 0..255 gram_var | 256..1535 W1T transpose | 1536..1727 W2T
//                (gram = hi/lo-split MFMA Gram + S-based power iteration;
//                 prep overlaps gram's latency stalls, stride-65 LDS = conflict-free)
//   p_mfma     : P(2048x5120 bf16) = Rbf @ W1T^T (dense, XCD-swizzled, m97 structure)
//   hsum_all   : Hsum(2048x2048 bf16) windowed relu-sums (short2)
//   out_split  : split-K=4 partials f32
//   out_reduce : out = sum partials + counted biases
// Train/test plans identical for SEQ=8,NF=4,SUB=10 -> is_test ignored.
// ---------------------------------------------------------------------------

typedef __attribute__((ext_vector_type(8))) short short8v;
typedef __attribute__((ext_vector_type(4))) short short4v;
typedef __attribute__((ext_vector_type(4))) float f32x4;

__device__ __forceinline__ short f2bf(float f) {
  uint32_t u = __float_as_uint(f);
  u += 0x7fffu + ((u >> 16) & 1u);      // RNE
  return (short)(u >> 16);
}
__device__ __forceinline__ float bf2f(short s) {
  return __uint_as_float(((uint32_t)(uint16_t)s) << 16);
}
__device__ __forceinline__ void gload16(const void* g, void* l) {
  __builtin_amdgcn_global_load_lds(
      (const __attribute__((address_space(1))) void*)g,
      (__attribute__((address_space(3))) void*)l, 16, 0, 0);
}

__device__ const int8_t ROWS4[12][5] = {
  {3, 0,1,2,3},
  {4, 0,1,2,3},{4, 1,2,3,4},
  {5, 0,1,2,3},{5, 1,2,3,4},{5, 2,3,4,5},
  {6, 0,1,2,3},{6, 1,2,3,4},{6, 2,3,4,5},{6, 3,4,5,6},
  {7, 0,2,4,6},{7, 1,3,5,7},
};
__device__ const int8_t ROWS3[15][4] = {
  {2, 0,1,2},
  {3, 0,1,2},{3, 1,2,3},
  {4, 0,1,2},{4, 1,2,3},{4, 2,3,4},
  {5, 0,2,4},{5, 1,3,5},
  {6, 0,2,4},{6, 1,3,5},{6, 2,4,6},
  {7, 0,2,4},{7, 1,3,5},{7, 2,4,6},{7, 3,5,7},
};
__device__ const int8_t ROWS2[19][3] = {
  {1, 0,1},
  {2, 0,1},{2, 1,2},
  {3, 0,2},{3, 1,3},
  {4, 0,2},{4, 1,3},{4, 2,4},
  {5, 0,3},{5, 1,4},{5, 2,5},
  {6, 0,3},{6, 1,4},{6, 2,5},{6, 3,6},
  {7, 0,4},{7, 1,5},{7, 2,6},{7, 3,7},
};
__device__ const int8_t ROWS1[36][2] = {
  {0,0},
  {1,0},{1,1},
  {2,0},{2,1},{2,2},
  {3,0},{3,1},{3,2},{3,3},
  {4,0},{4,1},{4,2},{4,3},{4,4},
  {5,0},{5,1},{5,2},{5,3},{5,4},{5,5},
  {6,0},{6,1},{6,2},{6,3},{6,4},{6,5},{6,6},
  {7,0},{7,1},{7,2},{7,3},{7,4},{7,5},{7,6},{7,7},
};
// window counts per (t, scale-index): si 0->s4, 1->s3, 2->s2, 3->s1
__device__ const float CNT[8][4] = {
  {0,0,0,1},{0,0,1,2},{0,1,2,3},{1,2,2,4},
  {2,3,3,5},{3,2,3,6},{4,3,4,7},{2,4,4,8},
};

// LDS offsets (bytes) for the gram path (79 KB); prep overlays the head.
#define GV_FH    0            // Fh [80 rows][128 bf16], swizzled, 20480 B
#define GV_FL    20480        // Fl, 20480 B
#define GV_S     40960        // S [80][84] f32, 26880 B
#define GV_XSUM  67840        // xsum [8][256] f32, 8192 B
#define GV_VB    76032        // vbuf [2][3][84] f32, 2016 B
#define GV_UU    78048        // uu [3][80] f32, 960 B
#define GV_SCAL  79008        // 12 f32
#define GV_SZ    79056

// ---------------------------------------------------------------------------
// Fat head kernel, 256 threads.
//   blk <  256   : gram_var (one block per batch)
//   blk < 1536   : W1T 64x64 transpose tile (LDS stride 65, conflict-free)
//   blk < 1728   : W2T build
__global__ __launch_bounds__(256) void head_fused(
    const float* __restrict__ init, const float* __restrict__ graph,
    const float* __restrict__ w1_4, const float* __restrict__ w1_3,
    const float* __restrict__ w1_2, const float* __restrict__ w1_1,
    const float* __restrict__ w2a, const float* __restrict__ w2b,
    const float* __restrict__ w2c, const float* __restrict__ w2d,
    short* __restrict__ Rbuf, short* __restrict__ W1T, short* __restrict__ W2T)
{
  __shared__ __align__(16) char smem[GV_SZ];
  const int tid = threadIdx.x;
  const int blk = blockIdx.x;

  if (blk >= 256) {
    if (blk < 1536) {
      // ---- W1T transpose: LDS stride 65 floats (2-way bank alias = free) ----
      float* sh = (float*)smem;                 // [64][65] = 16.6 KB
      const int pb = blk - 256;                 // 0..1279
      const int slice = pb >> 7, rem = pb & 127;
      const int k0 = (rem & 15) * 64, c0 = (rem >> 4) * 64;
      const float* W1; int j;
      if (slice < 4)      { W1 = w1_4; j = slice; }
      else if (slice < 7) { W1 = w1_3; j = slice - 4; }
      else if (slice < 9) { W1 = w1_2; j = slice - 7; }
      else                { W1 = w1_1; j = 0; }
#pragma unroll
      for (int q = tid; q < 1024; q += 256) {
        int r = q >> 4, cq = (q & 15) * 4;
        f32x4 v = *(const f32x4*)(W1 + (size_t)(j * 1024 + k0 + r) * 512 + c0 + cq);
        sh[r * 65 + cq + 0] = v.x; sh[r * 65 + cq + 1] = v.y;
        sh[r * 65 + cq + 2] = v.z; sh[r * 65 + cq + 3] = v.w;
      }
      __syncthreads();
#pragma unroll
      for (int q = tid; q < 1024; q += 256) {
        int cc = q >> 4, kq = (q & 15) * 4;
        short4v sv;
#pragma unroll
        for (int m = 0; m < 4; ++m) sv[m] = f2bf(sh[(kq + m) * 65 + cc]);
        *(short4v*)&W1T[(size_t)(slice * 512 + c0 + cc) * 1024 + k0 + kq] = sv;
      }
    } else {
      // ---- W2T build: col-padded [192][2048] ----
#pragma unroll
      for (int h = 0; h < 2; ++h) {
        int idx = (blk - 1536) * 2048 + tid * 8 + h * 4;
        int col = idx >> 11, kg = idx & 2047;
        int si = kg >> 9, kr = kg & 511;
        const float* w = (si == 0) ? w2a : (si == 1) ? w2b : (si == 2) ? w2c : w2d;
        short4v sv;
#pragma unroll
        for (int q = 0; q < 4; ++q)
          sv[q] = (col < 174) ? f2bf(w[(size_t)(kr + q) * 174 + col]) : (short)0;
        *(short4v*)&W2T[idx] = sv;
      }
    }
    return;
  }

  // ================= gram_var path (r7 verified) =================
  short* Fh  = (short*)(smem + GV_FH);
  short* Fl  = (short*)(smem + GV_FL);
  float* Sm  = (float*)(smem + GV_S);
  float* xsm = (float*)(smem + GV_XSUM);
  float* vb  = (float*)(smem + GV_VB);
  float* uum = (float*)(smem + GV_UU);
  float* scal= (float*)(smem + GV_SCAL);

  const int lane = tid & 63, w = tid >> 6;
  const int b = blk;
  const float* fb = init + (size_t)b * 80 * 256;

  int ti_[7], tj_[7];
#pragma unroll
  for (int q = 0; q < 7; ++q) {
    int tt = w + q * 4;
    int t5 = (tt < 25) ? tt : 0;
    ti_[q] = t5 / 5; tj_[q] = t5 % 5;
  }

  f32x4 acc[7];
#pragma unroll
  for (int q = 0; q < 7; ++q) acc[q] = (f32x4){0.f, 0.f, 0.f, 0.f};

  for (int ch = 0; ch < 2; ++ch) {
    __syncthreads();
    {
      const int t = tid >> 5, kq = tid & 31;
      const float* src = fb + (size_t)(t * 10) * 256 + ch * 128 + kq * 4;
      f32x4 sum = (f32x4){0.f, 0.f, 0.f, 0.f};
#pragma unroll
      for (int o = 0; o < 10; ++o) {
        f32x4 v = *(const f32x4*)(src + (size_t)o * 256);
        int r = t * 10 + o;
        int byte8 = r * 256 + ((kq * 8) ^ ((r & 7) << 4));
        short4v hv, lv;
#pragma unroll
        for (int e = 0; e < 4; ++e) {
          short h = f2bf(v[e]);
          hv[e] = h;
          lv[e] = f2bf(v[e] - bf2f(h));
        }
        *(short4v*)((char*)Fh + byte8) = hv;
        *(short4v*)((char*)Fl + byte8) = lv;
        sum += v;
      }
      *(f32x4*)(xsm + t * 256 + ch * 128 + kq * 4) = sum;
    }
    __syncthreads();

#pragma unroll
    for (int ks = 0; ks < 4; ++ks) {
      const int koff2 = (ks * 32 + (lane >> 4) * 8) * 2;
#pragma unroll
      for (int q = 0; q < 7; ++q) {
        const int tt = w + q * 4;
        if (tt < 25) {
          int ra = ti_[q] * 16 + (lane & 15);
          int rb = tj_[q] * 16 + (lane & 15);
          int ba = ra * 256 + (koff2 ^ ((ra & 7) << 4));
          int bb = rb * 256 + (koff2 ^ ((rb & 7) << 4));
          short8v ah = *(const short8v*)((char*)Fh + ba);
          short8v al = *(const short8v*)((char*)Fl + ba);
          short8v bh = *(const short8v*)((char*)Fh + bb);
          short8v bl = *(const short8v*)((char*)Fl + bb);
          acc[q] = __builtin_amdgcn_mfma_f32_16x16x32_bf16(ah, bh, acc[q], 0, 0, 0);
          acc[q] = __builtin_amdgcn_mfma_f32_16x16x32_bf16(ah, bl, acc[q], 0, 0, 0);
          acc[q] = __builtin_amdgcn_mfma_f32_16x16x32_bf16(al, bh, acc[q], 0, 0, 0);
        }
      }
    }
  }

#pragma unroll
  for (int q = 0; q < 7; ++q) {
    const int tt = w + q * 4;
    if (tt < 25) {
      int row0 = ti_[q] * 16 + (lane >> 4) * 4;
      int col = tj_[q] * 16 + (lane & 15);
#pragma unroll
      for (int r = 0; r < 4; ++r) Sm[(row0 + r) * 84 + col] = acc[q][r];
    }
  }
  if (tid < 240) vb[(0 * 3 + tid / 80) * 84 + (tid % 80)] = 1.0f;
  __syncthreads();

  const int pk = (tid < 240) ? tid / 80 : 0;
  const int pi = (tid < 240) ? tid % 80 : 0;
  int cur = 0;
  for (int it = 0; it < 5; ++it) {
    const bool last = (it == 4);
    float u = 0.f;
    if (tid < 240) {
      const float* Si = Sm + pi * 84;
      const float* vk = vb + (cur * 3 + pk) * 84;
#pragma unroll
      for (int q2 = 0; q2 < 20; ++q2) {
        f32x4 aa = *(const f32x4*)(Si + q2 * 4);
        f32x4 vv = *(const f32x4*)(vk + q2 * 4);
        u += aa.x * vv.x + aa.y * vv.y + aa.z * vv.z + aa.w * vv.w;
      }
    } else if (tid < 246) {
      int w2 = tid - 240;
      int k = (w2 < 3) ? w2 : w2 - 3;
      const float* vk = vb + (cur * 3 + k) * 84;
      float s = 0.f;
      if (w2 < 3) {
        for (int j2 = 0; j2 < 80; ++j2) s += vk[j2];
        scal[k] = s;                      // sigma
      } else {
        const float* Sk = Sm + k * 84;
        for (int j2 = 0; j2 < 80; ++j2) s += Sk[j2] * vk[j2];
        scal[3 + k] = s;                  // tau
      }
    }
    __syncthreads();
    if (tid < 240) {
      float sg = scal[pk], tu = scal[3 + pk];
      float un = u - Sm[pi * 84 + pk] * sg - tu + Sm[pk * 84 + pk] * sg;
      if (!last) vb[((cur ^ 1) * 3 + pk) * 84 + pi] = un * 6.103515625e-05f;  // 2^-14
      else       uum[pk * 80 + pi] = un;
    }
    __syncthreads();
    if (!last) cur ^= 1;
  }

  if (tid < 192) {
    const int k = tid >> 6, ln = tid & 63;
    float v1 = vb[(cur * 3 + k) * 84 + ln];
    float u1 = uum[k * 80 + ln];
    float a = u1 * v1, b2 = v1 * v1;
    if (ln < 16) {
      float v2 = vb[(cur * 3 + k) * 84 + 64 + ln];
      float u2 = uum[k * 80 + 64 + ln];
      a += u2 * v2; b2 += v2 * v2;
    }
#pragma unroll
    for (int m = 32; m >= 1; m >>= 1) {
      a += __shfl_xor(a, m);
      b2 += __shfl_xor(b2, m);
    }
    if (ln == 0) scal[9 + k] = a / b2;    // lambda
  }
  __syncthreads();
  if (tid == 0) {
    float L0 = -0.1f * scal[9], L1 = -0.1f * scal[10], L2 = -0.1f * scal[11];
    float m = fmaxf(L0, fmaxf(L1, L2));
    float e0 = expf(L0 - m), e1 = expf(L1 - m), e2 = expf(L2 - m);
    float inv = 1.0f / (e0 + e1 + e2);
    scal[6] = e0 * inv; scal[7] = e1 * inv; scal[8] = e2 * inv;
  }
  __syncthreads();

  {
    const float w0 = scal[6], w1 = scal[7], w2 = scal[8];
    const int d0 = (tid & 63) * 4;
#pragma unroll
    for (int p = 0; p < 2; ++p) {
      const int t = p * 4 + (tid >> 6);
      f32x4 xs = *(const f32x4*)(xsm + t * 256 + d0);
      f32x4 c0 = *(const f32x4*)(fb + 0 * 256 + d0);
      f32x4 c1 = *(const f32x4*)(fb + 1 * 256 + d0);
      f32x4 c2 = *(const f32x4*)(fb + 2 * 256 + d0);
      f32x4 go = *(const f32x4*)(graph + (size_t)(b * 8 + t) * 256 + d0);
      size_t rb = ((size_t)(b * 8 + t)) * 1024;
      short4v s0, s1, s2, s3;
#pragma unroll
      for (int q = 0; q < 4; ++q) {
        float xq = xs[q];
        s0[q] = f2bf(fmaxf(w0 * (xq - 10.f * c0[q]), 0.f));
        s1[q] = f2bf(fmaxf(w1 * (xq - 10.f * c1[q]), 0.f));
        s2[q] = f2bf(fmaxf(w2 * (xq - 10.f * c2[q]), 0.f));
        s3[q] = f2bf(fmaxf(go[q], 0.f));
      }
      *(short4v*)&Rbuf[rb + 0 + d0]   = s0;
      *(short4v*)&Rbuf[rb + 256 + d0] = s1;
      *(short4v*)&Rbuf[rb + 512 + d0] = s2;
      *(short4v*)&Rbuf[rb + 768 + d0] = s3;
    }
  }
}

// ---------------------------------------------------------------------------
// P(2048 x 5120) bf16 = Rbf(2048x1024) @ W1T^T; 128x128 tile, BK=32, 4 waves.
__global__ __launch_bounds__(256) void p_mfma(
    const short* __restrict__ A, const short* __restrict__ W1T,
    short* __restrict__ P)
{
  __shared__ short As[128 * 32];
  __shared__ short Bs[128 * 32];
  const int id = blockIdx.x + blockIdx.y * 40;     // 640 = 8 XCD * 80
  const int nid = (id & 7) * 80 + (id >> 3);
  const int bx = nid >> 4, by = nid & 15;
  const int tid = threadIdx.x, lane = tid & 63, w = tid >> 6;
  const int wr = w >> 1, wc = w & 1;
  const int rowBase = by * 128;
  const short* Bp = W1T + (size_t)bx * 128 * 1024;
  const int rA = w * 16 + (lane >> 2);
  const int kkA = (lane & 3) * 8;

  f32x4 acc[4][4];
#pragma unroll
  for (int m = 0; m < 4; ++m)
#pragma unroll
    for (int n = 0; n < 4; ++n) acc[m][n] = (f32x4){0.f, 0.f, 0.f, 0.f};

  for (int k0 = 0; k0 < 1024; k0 += 32) {
    __syncthreads();
    gload16(A + (size_t)(rowBase + rA) * 1024 + k0 + kkA, As + w * 512);
    gload16(A + (size_t)(rowBase + 64 + rA) * 1024 + k0 + kkA, As + 2048 + w * 512);
    gload16(Bp + (size_t)rA * 1024 + k0 + kkA, Bs + w * 512);
    gload16(Bp + (size_t)(64 + rA) * 1024 + k0 + kkA, Bs + 2048 + w * 512);
    __syncthreads();
    short8v a[4], bv[4];
#pragma unroll
    for (int m = 0; m < 4; ++m)
      a[m] = *(const short8v*)(As + (wr * 64 + m * 16 + (lane & 15)) * 32 + (lane >> 4) * 8);
#pragma unroll
    for (int n = 0; n < 4; ++n)
      bv[n] = *(const short8v*)(Bs + (wc * 64 + n * 16 + (lane & 15)) * 32 + (lane >> 4) * 8);
#pragma unroll
    for (int m = 0; m < 4; ++m)
#pragma unroll
      for (int n = 0; n < 4; ++n)
        acc[m][n] = __builtin_amdgcn_mfma_f32_16x16x32_bf16(a[m], bv[n], acc[m][n], 0, 0, 0);
  }

  const int colG = bx * 128 + wc * 64;
#pragma unroll
  for (int m = 0; m < 4; ++m) {
    int row = rowBase + wr * 64 + m * 16 + (lane >> 4) * 4;
#pragma unroll
    for (int n = 0; n < 4; ++n) {
      int col = colG + n * 16 + (lane & 15);
#pragma unroll
      for (int r = 0; r < 4; ++r)
        P[(size_t)(row + r) * 5120 + col] = f2bf(acc[m][n][r]);
    }
  }
}

// ---------------------------------------------------------------------------
// Hsum[row][si*512+c] bf16; thread owns 2 consecutive cols (short2 loads).
__global__ __launch_bounds__(256) void hsum_all(
    const short* __restrict__ P,
    const float* __restrict__ b1a, const float* __restrict__ b1b,
    const float* __restrict__ b1c, const float* __restrict__ b1d,
    short* __restrict__ Hsum)
{
  const int row = blockIdx.x, t = row & 7, base = row - t;
  const int c0 = threadIdx.x * 2;
  const size_t prow = (size_t)base * 5120;

  {  // si=0, s=4
    float2 bb = *(const float2*)(b1a + c0);
    float a0 = 0.f, a1 = 0.f;
    for (int r = 0; r < 12; ++r) {
      if (ROWS4[r][0] != t) continue;
      float h0 = bb.x, h1 = bb.y;
#pragma unroll
      for (int jj = 0; jj < 4; ++jj) {
        const short2 pv = *(const short2*)(P + prow + (size_t)ROWS4[r][1 + jj] * 5120 + jj * 512 + c0);
        h0 += bf2f(pv.x); h1 += bf2f(pv.y);
      }
      a0 += fmaxf(h0, 0.f); a1 += fmaxf(h1, 0.f);
    }
    uint32_t wv = (uint32_t)(uint16_t)f2bf(a0) | ((uint32_t)(uint16_t)f2bf(a1) << 16);
    *(uint32_t*)&Hsum[(size_t)row * 2048 + c0] = wv;
  }
  {  // si=1, s=3
    float2 bb = *(const float2*)(b1b + c0);
    float a0 = 0.f, a1 = 0.f;
    for (int r = 0; r < 15; ++r) {
      if (ROWS3[r][0] != t) continue;
      float h0 = bb.x, h1 = bb.y;
#pragma unroll
      for (int jj = 0; jj < 3; ++jj) {
        const short2 pv = *(const short2*)(P + prow + (size_t)ROWS3[r][1 + jj] * 5120 + 2048 + jj * 512 + c0);
        h0 += bf2f(pv.x); h1 += bf2f(pv.y);
      }
      a0 += fmaxf(h0, 0.f); a1 += fmaxf(h1, 0.f);
    }
    uint32_t wv = (uint32_t)(uint16_t)f2bf(a0) | ((uint32_t)(uint16_t)f2bf(a1) << 16);
    *(uint32_t*)&Hsum[(size_t)row * 2048 + 512 + c0] = wv;
  }
  {  // si=2, s=2
    float2 bb = *(const float2*)(b1c + c0);
    float a0 = 0.f, a1 = 0.f;
    for (int r = 0; r < 19; ++r) {
      if (ROWS2[r][0] != t) continue;
      float h0 = bb.x, h1 = bb.y;
#pragma unroll
      for (int jj = 0; jj < 2; ++jj) {
        const short2 pv = *(const short2*)(P + prow + (size_t)ROWS2[r][1 + jj] * 5120 + 3584 + jj * 512 + c0);
        h0 += bf2f(pv.x); h1 += bf2f(pv.y);
      }
      a0 += fmaxf(h0, 0.f); a1 += fmaxf(h1, 0.f);
    }
    uint32_t wv = (uint32_t)(uint16_t)f2bf(a0) | ((uint32_t)(uint16_t)f2bf(a1) << 16);
    *(uint32_t*)&Hsum[(size_t)row * 2048 + 1024 + c0] = wv;
  }
  {  // si=3, s=1
    float2 bb = *(const float2*)(b1d + c0);
    float a0 = 0.f, a1 = 0.f;
    for (int r = 0; r < 36; ++r) {
      if (ROWS1[r][0] != t) continue;
      const short2 pv = *(const short2*)(P + prow + (size_t)ROWS1[r][1] * 5120 + 4608 + c0);
      a0 += fmaxf(bb.x + bf2f(pv.x), 0.f);
      a1 += fmaxf(bb.y + bf2f(pv.y), 0.f);
    }
    uint32_t wv = (uint32_t)(uint16_t)f2bf(a0) | ((uint32_t)(uint16_t)f2bf(a1) << 16);
    *(uint32_t*)&Hsum[(size_t)row * 2048 + 1536 + c0] = wv;
  }
}

// ---------------------------------------------------------------------------
// Split-K out GEMM: partial[z][2048][192] = Hsum[:, z*512:(z+1)*512] @ W2T^T.
__global__ __launch_bounds__(256) void out_split(
    const short* __restrict__ H, const short* __restrict__ W2T,
    float* __restrict__ partial)
{
  __shared__ short As[128 * 32];
  __shared__ short Bs[64 * 32];
  const int tid = threadIdx.x, lane = tid & 63, w = tid >> 6;
  const int wr = w >> 1, wc = w & 1;
  const int rowBase = blockIdx.y * 128, colBase = blockIdx.x * 64;
  const int kBase = blockIdx.z * 512;
  const int rA = w * 16 + (lane >> 2);
  const int kkA = (lane & 3) * 8;

  f32x4 acc[4][2];
#pragma unroll
  for (int m = 0; m < 4; ++m)
#pragma unroll
    for (int n = 0; n < 2; ++n) acc[m][n] = (f32x4){0.f, 0.f, 0.f, 0.f};

  for (int k0 = 0; k0 < 512; k0 += 32) {
    const int kg = kBase + k0;
    __syncthreads();
    gload16(H + (size_t)(rowBase + rA) * 2048 + kg + kkA, As + w * 512);
    gload16(H + (size_t)(rowBase + 64 + rA) * 2048 + kg + kkA, As + 2048 + w * 512);
    gload16(W2T + (size_t)(colBase + rA) * 2048 + kg + kkA, Bs + w * 512);
    __syncthreads();
    short8v a[4], bv[2];
#pragma unroll
    for (int m = 0; m < 4; ++m)
      a[m] = *(const short8v*)(As + (wr * 64 + m * 16 + (lane & 15)) * 32 + (lane >> 4) * 8);
#pragma unroll
    for (int n = 0; n < 2; ++n)
      bv[n] = *(const short8v*)(Bs + (wc * 32 + n * 16 + (lane & 15)) * 32 + (lane >> 4) * 8);
#pragma unroll
    for (int m = 0; m < 4; ++m)
#pragma unroll
      for (int n = 0; n < 2; ++n)
        acc[m][n] = __builtin_amdgcn_mfma_f32_16x16x32_bf16(a[m], bv[n], acc[m][n], 0, 0, 0);
  }

  float* pz = partial + (size_t)blockIdx.z * 2048 * 192;
#pragma unroll
  for (int n = 0; n < 2; ++n) {
    int col = colBase + wc * 32 + n * 16 + (lane & 15);
#pragma unroll
    for (int m = 0; m < 4; ++m) {
      int row0 = rowBase + wr * 64 + m * 16 + (lane >> 4) * 4;
#pragma unroll
      for (int r = 0; r < 4; ++r)
        pz[(size_t)(row0 + r) * 192 + col] = acc[m][n][r];
    }
  }
}

// ---------------------------------------------------------------------------
__global__ __launch_bounds__(256) void out_reduce(
    const float* __restrict__ partial,
    const float* __restrict__ b2a, const float* __restrict__ b2b,
    const float* __restrict__ b2c, const float* __restrict__ b2d,
    float* __restrict__ out)
{
  const int row = blockIdx.x, col = threadIdx.x;
  if (col >= 174) return;
  const size_t o = (size_t)row * 192 + col;
  float s = partial[o] + partial[o + (size_t)2048 * 192]
          + partial[o + (size_t)4096 * 192] + partial[o + (size_t)6144 * 192];
  int tt = row & 7;
  float bias = CNT[tt][0] * b2a[col] + CNT[tt][1] * b2b[col]
             + CNT[tt][2] * b2c[col] + CNT[tt][3] * b2d[col];
  out[(size_t)row * 174 + col] = s + bias;
}

// ---------------------------------------------------------------------------
extern "C" void kernel_launch(void* const* d_in, const int* in_sizes, int n_in,
                              void* d_out, int out_size, void* d_ws, size_t ws_size,
                              hipStream_t stream) {
  const float* graph = (const float*)d_in[0];
  const float* init  = (const float*)d_in[1];
  const float* w1[4] = {(const float*)d_in[3],  (const float*)d_in[7],
                        (const float*)d_in[11], (const float*)d_in[15]};
  const float* b1[4] = {(const float*)d_in[4],  (const float*)d_in[8],
                        (const float*)d_in[12], (const float*)d_in[16]};
  const float* w2[4] = {(const float*)d_in[5],  (const float*)d_in[9],
                        (const float*)d_in[13], (const float*)d_in[17]};
  const float* b2[4] = {(const float*)d_in[6],  (const float*)d_in[10],
                        (const float*)d_in[14], (const float*)d_in[18]};
  float* out = (float*)d_out;

  char* ws = (char*)d_ws;
  short* Rbf  = (short*)(ws + 0);                    // 4 MiB   (dead after p_mfma)
  short* W1T  = (short*)(ws + ((size_t)4  << 20));   // 10 MiB  (dead after p_mfma)
  short* P    = (short*)(ws + ((size_t)14 << 20));   // 20 MiB  (dead after hsum_all)
  short* W2T  = (short*)(ws + ((size_t)34 << 20));   // 0.75 MiB
  short* Hsum = (short*)(ws + 0);                    // 8 MiB   (over Rbf/W1T head)
  float* Part = (float*)(ws + ((size_t)8 << 20));    // 6.29 MiB (over W1T tail)

  head_fused<<<1728, 256, 0, stream>>>(init, graph,
                                       w1[0], w1[1], w1[2], w1[3],
                                       w2[0], w2[1], w2[2], w2[3],
                                       Rbf, W1T, W2T);

  p_mfma<<<dim3(40, 16), 256, 0, stream>>>(Rbf, W1T, P);

  hsum_all<<<2048, 256, 0, stream>>>(P, b1[0], b1[1], b1[2], b1[3], Hsum);

  out_split<<<dim3(3, 16, 4), 256, 0, stream>>>(Hsum, W2T, Part);

  out_reduce<<<2048, 256, 0, stream>>>(Part, b2[0], b2[1], b2[2], b2[3], out);
}